// Round 11
// baseline (185.252 us; speedup 1.0000x reference)
//
#include <hip/hip_runtime.h>

#define DDIM 128

typedef __bf16 bf16x8 __attribute__((ext_vector_type(8)));
typedef float  floatx4 __attribute__((ext_vector_type(4)));

__device__ inline unsigned short f2bf(float f) {      // RNE fp32 -> bf16 bits
    unsigned u = __builtin_bit_cast(unsigned, f);
    u += 0x7fffu + ((u >> 16) & 1u);
    return (unsigned short)(u >> 16);
}

// ---------------------------------------------------------------------------
// Kernel 1: one N-half of [U|V] = z @ W_combined per block (bf16 MFMA
// 16x16x32), int8 out + per-node scales. Composition of the three best
// measured variants:
//  - half-split + 32 KB LDS W-frag staging  (r5-sub: best total 140.8)
//  - direct permuted int8 stores, no epilogue LDS (r6 discovery)
//  - z-prefetch across grid-stride chunks   (r10 technique)
// Store layout (permuted): byte mrow*8+nt <- col nt*16+mrow; 8 B/lane, full
// 128-B lines per 16-lane group. Edge kernel un-permutes via W2[j*16+p].
// ---------------------------------------------------------------------------
__global__ __launch_bounds__(256, 3) void precompute_uv_mfma_q8(
    const float* __restrict__ z, const float* __restrict__ W1,
    const float* __restrict__ b1,
    signed char* __restrict__ U8, signed char* __restrict__ V8,
    float* __restrict__ u_scale, float* __restrict__ v_scale,
    int N, int nchunks)
{
    __shared__ unsigned short WsF[32 * 64 * 8];   // 32 KiB: this half's B-frags

    const int t    = threadIdx.x;
    const int lane = t & 63;
    const int w    = t >> 6;            // wave 0..3
    const int mrow = lane & 15;
    const int quad = lane >> 4;
    const int half = blockIdx.x;        // 0 -> U, 1 -> V
    signed char* __restrict__ dst8 = half ? V8 : U8;
    float*       __restrict__ dscl = half ? v_scale : u_scale;
    const float* __restrict__ Wh   = W1 + (size_t)half * DDIM * DDIM;

    // ---- stage W-half fragments (once per block) ----
    {
        const int nlow = mrow;
        const int kq   = quad;
        #pragma unroll
        for (int i = 0; i < 8; ++i) {
            const int ntks = w + i * 4;              // 0..31
            const int nt = ntks >> 2, ks = ntks & 3;
            const int n  = nt * 16 + nlow;
            const int kb = ks * 32 + kq * 8;
            unsigned short frag[8];
            #pragma unroll
            for (int j = 0; j < 8; ++j)
                frag[j] = f2bf(Wh[(size_t)(kb + j) * DDIM + n]);
            *(uint4*)&WsF[(ntks * 64 + lane) * 8] = *(const uint4*)frag;
        }
    }

    float bu[8];
    #pragma unroll
    for (int nt = 0; nt < 8; ++nt)
        bu[nt] = half ? 0.f : b1[nt * 16 + mrow];

    __syncthreads();

    int chunk = blockIdx.y;
    if (chunk >= nchunks) return;
    const int koff = quad * 8;

    float4 raw[8];
    {   // load current chunk's z rows (raw fp32)
        int grow = chunk * 64 + w * 16 + mrow; if (grow > N - 1) grow = N - 1;
        const float* zrow = z + (size_t)grow * DDIM;
        #pragma unroll
        for (int ks = 0; ks < 4; ++ks) {
            raw[ks * 2]     = *(const float4*)(zrow + ks * 32 + koff);
            raw[ks * 2 + 1] = *(const float4*)(zrow + ks * 32 + koff + 4);
        }
    }

    while (true) {
        const int next = chunk + gridDim.y;
        const bool have_next = next < nchunks;

        // current raw -> A fragments
        bf16x8 afrag[4];
        #pragma unroll
        for (int ks = 0; ks < 4; ++ks) {
            const float4 x0 = raw[ks * 2], x1 = raw[ks * 2 + 1];
            unsigned short a[8];
            a[0] = f2bf(x0.x); a[1] = f2bf(x0.y); a[2] = f2bf(x0.z); a[3] = f2bf(x0.w);
            a[4] = f2bf(x1.x); a[5] = f2bf(x1.y); a[6] = f2bf(x1.z); a[7] = f2bf(x1.w);
            afrag[ks] = __builtin_bit_cast(bf16x8, *(const uint4*)a);
        }

        // prefetch next chunk's z -- overlaps MFMA + epilogue below
        float4 raw2[8];
        if (have_next) {
            int grow = next * 64 + w * 16 + mrow; if (grow > N - 1) grow = N - 1;
            const float* zrow = z + (size_t)grow * DDIM;
            #pragma unroll
            for (int ks = 0; ks < 4; ++ks) {
                raw2[ks * 2]     = *(const float4*)(zrow + ks * 32 + koff);
                raw2[ks * 2 + 1] = *(const float4*)(zrow + ks * 32 + koff + 4);
            }
        }

        floatx4 acc[8];
        #pragma unroll
        for (int nt = 0; nt < 8; ++nt) acc[nt] = (floatx4){0.f, 0.f, 0.f, 0.f};

        #pragma unroll
        for (int ks = 0; ks < 4; ++ks) {
            #pragma unroll
            for (int nt = 0; nt < 8; ++nt) {
                const bf16x8 b = __builtin_bit_cast(bf16x8,
                    *(const uint4*)&WsF[((nt * 4 + ks) * 64 + lane) * 8]);
                acc[nt] = __builtin_amdgcn_mfma_f32_16x16x32_bf16(afrag[ks], b, acc[nt], 0, 0, 0);
            }
        }

        // quantize + direct permuted stores
        // C-layout: (nt,r) -> local row quad*4+r, col nt*16+mrow
        const int m0 = chunk * 64 + w * 16;
        #pragma unroll
        for (int r = 0; r < 4; ++r) {
            float v[8];
            #pragma unroll
            for (int nt = 0; nt < 8; ++nt) v[nt] = acc[nt][r] + bu[nt];

            float mx = 0.f;
            #pragma unroll
            for (int nt = 0; nt < 8; ++nt) mx = fmaxf(mx, fabsf(v[nt]));
            #pragma unroll
            for (int m = 1; m < 16; m <<= 1)
                mx = fmaxf(mx, __shfl_xor(mx, m, 16));
            mx = fmaxf(mx, 1e-20f);
            const float inv = 127.f / mx;

            unsigned char bytes[8];
            #pragma unroll
            for (int nt = 0; nt < 8; ++nt)
                bytes[nt] = (unsigned char)(((int)rintf(v[nt] * inv)) & 0xff);

            const int grow = m0 + quad * 4 + r;
            if (grow < N) {
                *(unsigned long long*)&dst8[(size_t)grow * DDIM + mrow * 8] =
                    *(const unsigned long long*)bytes;
                if (mrow == 0) dscl[grow] = mx * (1.f / 127.f);
            }
        }

        if (!have_next) break;
        #pragma unroll
        for (int i = 0; i < 8; ++i) raw[i] = raw2[i];
        chunk = next;
    }
}

// ---------------------------------------------------------------------------
// Kernel 2: per-edge gather (int8 U/V + per-node scales) + relu + dot(W2).
// 16 lanes per group, 4 edges per group. Lane p's 8 bytes are permuted cols
// j*16+p, so ww[j] = W2[j*16+p].
// ---------------------------------------------------------------------------
__global__ __launch_bounds__(256) void edge_kernel_i8(
    const int* __restrict__ ei,
    const signed char* __restrict__ U8, const signed char* __restrict__ V8,
    const float* __restrict__ u_scale, const float* __restrict__ v_scale,
    const float* __restrict__ W2, const float* __restrict__ b2,
    float* __restrict__ out, int E)
{
    const int t  = threadIdx.x;
    const int p  = t & 15;
    const int g0 = (blockIdx.x * 16 + (t >> 4)) * 4;   // first of 4 edges

    float ww[8];
    #pragma unroll
    for (int j = 0; j < 8; ++j) ww[j] = W2[j * 16 + p];

    if (g0 >= E) return;

    int rows[4], cols[4];
    if (g0 + 3 < E) {
        const int4 r4 = *(const int4*)(ei + g0);
        const int4 c4 = *(const int4*)(ei + (size_t)E + g0);
        rows[0]=r4.x; rows[1]=r4.y; rows[2]=r4.z; rows[3]=r4.w;
        cols[0]=c4.x; cols[1]=c4.y; cols[2]=c4.z; cols[3]=c4.w;
    } else {
        #pragma unroll
        for (int i = 0; i < 4; ++i) {
            const int gi = (g0 + i < E) ? (g0 + i) : (E - 1);
            rows[i] = ei[gi];
            cols[i] = ei[(size_t)E + gi];
        }
    }

    uint2 uu[4], vv[4];
    #pragma unroll
    for (int i = 0; i < 4; ++i)
        uu[i] = *(const uint2*)(U8 + (size_t)rows[i] * DDIM + p * 8);
    #pragma unroll
    for (int i = 0; i < 4; ++i)
        vv[i] = *(const uint2*)(V8 + (size_t)cols[i] * DDIM + p * 8);

    float su[4], sv[4];
    #pragma unroll
    for (int i = 0; i < 4; ++i) { su[i] = u_scale[rows[i]]; sv[i] = v_scale[cols[i]]; }

    const float bias = b2[0];

    #pragma unroll
    for (int i = 0; i < 4; ++i) {
        const signed char* us = (const signed char*)&uu[i];
        const signed char* vs = (const signed char*)&vv[i];
        float s = 0.f;
        #pragma unroll
        for (int j = 0; j < 8; ++j) {
            const float h = fmaf(sv[i], (float)vs[j], su[i] * (float)us[j]);
            s = fmaf(fmaxf(h, 0.f), ww[j], s);
        }
        #pragma unroll
        for (int off = 8; off > 0; off >>= 1)
            s += __shfl_down(s, off, 16);
        if (p == 0 && g0 + i < E) out[g0 + i] = s + bias;
    }
}

// ---------------------------------------------------------------------------
// Fallback (ws too small): fused per-edge fp32 GEMV (known-correct path).
// ---------------------------------------------------------------------------
__global__ __launch_bounds__(256) void edge_fused_fallback(
    const float* __restrict__ z, const int* __restrict__ ei,
    const float* __restrict__ W1, const float* __restrict__ b1,
    const float* __restrict__ W2, const float* __restrict__ b2,
    float* __restrict__ out, int N, int E)
{
    const int tid  = blockIdx.x * 256 + threadIdx.x;
    const int e    = tid >> 6;
    const int lane = tid & 63;
    if (e >= E) return;

    const int row = ei[e];
    const int col = ei[(size_t)E + e];
    const float* zr = z + (size_t)row * DDIM;
    const float* zc = z + (size_t)col * DDIM;

    float h0 = b1[lane];
    float h1 = b1[lane + 64];
    for (int k = 0; k < DDIM; ++k) {
        const float a = zr[k];
        const float b = zc[k];
        h0 = fmaf(a, W1[k * DDIM + lane],               h0);
        h0 = fmaf(b, W1[(DDIM + k) * DDIM + lane],      h0);
        h1 = fmaf(a, W1[k * DDIM + lane + 64],          h1);
        h1 = fmaf(b, W1[(DDIM + k) * DDIM + lane + 64], h1);
    }
    float s = fmaxf(h0, 0.f) * W2[lane] + fmaxf(h1, 0.f) * W2[lane + 64];
    #pragma unroll
    for (int off = 32; off > 0; off >>= 1)
        s += __shfl_down(s, off, 64);
    if (lane == 0) out[e] = s + b2[0];
}

extern "C" void kernel_launch(void* const* d_in, const int* in_sizes, int n_in,
                              void* d_out, int out_size, void* d_ws, size_t ws_size,
                              hipStream_t stream)
{
    const float* z  = (const float*)d_in[0];
    const int*   ei = (const int*)d_in[1];       // int32 per harness convention
    const float* W1 = (const float*)d_in[2];
    const float* b1 = (const float*)d_in[3];
    const float* W2 = (const float*)d_in[4];
    const float* b2 = (const float*)d_in[5];
    float*       out = (float*)d_out;

    const int N = in_sizes[0] / DDIM;
    const int E = in_sizes[1] / 2;

    const size_t n128 = (size_t)N * DDIM;
    const size_t need = 2 * n128 + 2 * (size_t)N * sizeof(float) + 256;
    if (ws_size >= need) {
        signed char* U8 = (signed char*)d_ws;
        signed char* V8 = U8 + n128;
        float* usc = (float*)(((size_t)(V8 + n128) + 255) & ~(size_t)255);
        float* vsc = usc + N;

        const int nchunks = (N + 63) / 64;
        // (2 halves, 384): 768 blocks; 32 KB LDS + ~150 VGPR -> 3 blocks/CU.
        hipLaunchKernelGGL(precompute_uv_mfma_q8, dim3(2, 384), dim3(256), 0, stream,
                           z, W1, b1, U8, V8, usc, vsc, N, nchunks);
        hipLaunchKernelGGL(edge_kernel_i8, dim3((E + 63) / 64), dim3(256), 0, stream,
                           ei, U8, V8, usc, vsc, W2, b2, out, E);
    } else {
        hipLaunchKernelGGL(edge_fused_fallback, dim3((E + 3) / 4), dim3(256), 0, stream,
                           z, ei, W1, b1, W2, b2, out, N, E);
    }
}